// Round 2
// baseline (1277.802 us; speedup 1.0000x reference)
//
#include <hip/hip_runtime.h>
#include <hip/hip_fp16.h>

typedef __attribute__((ext_vector_type(8))) _Float16 f16x8;
typedef __attribute__((ext_vector_type(4))) _Float16 f16x4;
typedef __attribute__((ext_vector_type(4))) float f32x4;

#define TILE_M 128
#define TILE_N 128
#define TILE_K 32
#define LDSK   40   // TILE_K + 8 pad: stride 80B -> rows spread across banks

__device__ __forceinline__ void split4(const f32x4 v, f16x4 &h, f16x4 &l) {
    #pragma unroll
    for (int i = 0; i < 4; ++i) {
        float a = v[i];
        _Float16 hh = (_Float16)a;        // v_cvt_f16_f32 (RNE)
        h[i] = hh;
        l[i] = (_Float16)(a - (float)hh); // residual, rel err ~2^-24
    }
}

// C[m][n] = act( sum_k A[m][k] * B[n][k] + bias[n] )  -- B row-major [N][K] (A*B^T)
// fp32 emulated via f16 hi/lo split: hi*hi + hi*lo + lo*hi (3 MFMAs, fp32 accumulate).
template<bool RELU, bool NGUARD>
__global__ __launch_bounds__(256, 2)
void gemm_split3(const float* __restrict__ A, const float* __restrict__ B,
                 const float* __restrict__ bias, float* __restrict__ C,
                 int K, int ldc, int Nreal)
{
    __shared__ _Float16 Ah[TILE_M][LDSK];
    __shared__ _Float16 Al[TILE_M][LDSK];
    __shared__ _Float16 Bh[TILE_N][LDSK];
    __shared__ _Float16 Bl[TILE_N][LDSK];

    const int tid  = threadIdx.x;
    const int lane = tid & 63;
    const int wave = tid >> 6;
    const int wr   = wave >> 1;         // 2x2 wave grid
    const int wc   = wave & 1;
    const int m0   = blockIdx.x * TILE_M;
    const int n0   = blockIdx.y * TILE_N;

    const int srow = tid >> 3;          // 0..31  staging row
    const int scol = (tid & 7) << 2;    // 0,4,...,28 staging col (float4)

    const int fr = lane & 15;           // fragment non-K index
    const int fg = lane >> 4;           // k-group 0..3

    f32x4 acc[4][4] = {};

    for (int kt = 0; kt < K; kt += TILE_K) {
        __syncthreads();   // protect LDS against previous iteration's readers
        // ---- stage A tile: 128x32 fp32 -> hi/lo f16 ----
        #pragma unroll
        for (int p = 0; p < 4; ++p) {
            const int row = srow + p * 32;
            f32x4 v = *(const f32x4*)(A + (size_t)(m0 + row) * K + kt + scol);
            f16x4 hv, lv;
            split4(v, hv, lv);
            *(f16x4*)&Ah[row][scol] = hv;
            *(f16x4*)&Al[row][scol] = lv;
        }
        // ---- stage B tile ----
        #pragma unroll
        for (int p = 0; p < 4; ++p) {
            const int row = srow + p * 32;
            f32x4 v = {0.f, 0.f, 0.f, 0.f};
            if (!NGUARD || (n0 + row) < Nreal)
                v = *(const f32x4*)(B + (size_t)(n0 + row) * K + kt + scol);
            f16x4 hv, lv;
            split4(v, hv, lv);
            *(f16x4*)&Bh[row][scol] = hv;
            *(f16x4*)&Bl[row][scol] = lv;
        }
        __syncthreads();

        // ---- compute: per wave 64x64 = 4x4 fragments of 16x16x32 ----
        f16x8 ah[4], al[4];
        #pragma unroll
        for (int mi = 0; mi < 4; ++mi) {
            const int r = wr * 64 + mi * 16 + fr;
            ah[mi] = *(const f16x8*)&Ah[r][fg * 8];
            al[mi] = *(const f16x8*)&Al[r][fg * 8];
        }
        #pragma unroll
        for (int ni = 0; ni < 4; ++ni) {
            const int r = wc * 64 + ni * 16 + fr;
            const f16x8 bh = *(const f16x8*)&Bh[r][fg * 8];
            const f16x8 bl = *(const f16x8*)&Bl[r][fg * 8];
            #pragma unroll
            for (int mi = 0; mi < 4; ++mi) {
                acc[mi][ni] = __builtin_amdgcn_mfma_f32_16x16x32_f16(ah[mi], bh, acc[mi][ni], 0, 0, 0);
                acc[mi][ni] = __builtin_amdgcn_mfma_f32_16x16x32_f16(ah[mi], bl, acc[mi][ni], 0, 0, 0);
                acc[mi][ni] = __builtin_amdgcn_mfma_f32_16x16x32_f16(al[mi], bh, acc[mi][ni], 0, 0, 0);
            }
        }
    }

    // ---- epilogue: bias (+ReLU), guarded store ----
    // D mapping (HW-verified): n = lane&15, m = (lane>>4)*4 + reg
    #pragma unroll
    for (int ni = 0; ni < 4; ++ni) {
        const int n = n0 + wc * 64 + ni * 16 + fr;
        if (NGUARD && n >= Nreal) continue;
        const float bv = bias[n];
        #pragma unroll
        for (int mi = 0; mi < 4; ++mi) {
            #pragma unroll
            for (int j = 0; j < 4; ++j) {
                const int m = m0 + wr * 64 + mi * 16 + fg * 4 + j;
                float val = acc[mi][ni][j] + bv;
                if (RELU) val = fmaxf(val, 0.f);
                C[(size_t)m * ldc + n] = val;
            }
        }
    }
}

// In-place row softmax: one wave per row, 16 elems per lane (cols <= 1024).
__global__ __launch_bounds__(256)
void softmax_rows(float* __restrict__ out, int rows, int cols)
{
    const int lane = threadIdx.x & 63;
    const int row  = blockIdx.x * 4 + (threadIdx.x >> 6);
    if (row >= rows) return;
    float* p = out + (size_t)row * cols;

    float v[16];
    float mx = -3.4e38f;
    #pragma unroll
    for (int j = 0; j < 16; ++j) {
        const int c = lane + j * 64;
        v[j] = (c < cols) ? p[c] : -3.4e38f;
        mx = fmaxf(mx, v[j]);
    }
    #pragma unroll
    for (int off = 32; off > 0; off >>= 1)
        mx = fmaxf(mx, __shfl_xor(mx, off));

    float s = 0.f;
    #pragma unroll
    for (int j = 0; j < 16; ++j) {
        const int c = lane + j * 64;
        const float e = (c < cols) ? __expf(v[j] - mx) : 0.f;
        v[j] = e;
        s += e;
    }
    #pragma unroll
    for (int off = 32; off > 0; off >>= 1)
        s += __shfl_xor(s, off);

    const float inv = 1.f / s;
    #pragma unroll
    for (int j = 0; j < 16; ++j) {
        const int c = lane + j * 64;
        if (c < cols) p[c] = v[j] * inv;
    }
}

extern "C" void kernel_launch(void* const* d_in, const int* in_sizes, int n_in,
                              void* d_out, int out_size, void* d_ws, size_t ws_size,
                              hipStream_t stream)
{
    const float* x  = (const float*)d_in[0];   // [8192, 4096]
    const float* w1 = (const float*)d_in[1];   // [4096, 4096]
    const float* b1 = (const float*)d_in[2];   // [4096]
    const float* w2 = (const float*)d_in[3];   // [1000, 4096]
    const float* b2 = (const float*)d_in[4];   // [1000]
    float* out = (float*)d_out;                // [8192, 1000] fp32
    float* act = (float*)d_ws;                 // [8192, 4096] fp32 scratch (134 MB)

    const dim3 blk(256, 1, 1);

    // GEMM1: act = relu(x @ w1^T + b1)   M=8192 N=4096 K=4096
    hipLaunchKernelGGL((gemm_split3<true, false>), dim3(64, 32), blk, 0, stream,
                       x, w1, b1, act, 4096, 4096, 4096);
    // GEMM2: logits = act @ w2^T + b2    M=8192 N=1000 (tiled to 1024) K=4096
    hipLaunchKernelGGL((gemm_split3<false, true>), dim3(64, 8), blk, 0, stream,
                       act, w2, b2, out, 4096, 1000, 1000);
    // softmax rows in-place on d_out
    hipLaunchKernelGGL(softmax_rows, dim3(2048), blk, 0, stream, out, 8192, 1000);
}

// Round 3
// 1036.365 us; speedup vs baseline: 1.2330x; 1.2330x over previous
//
#include <hip/hip_runtime.h>
#include <hip/hip_fp16.h>
#include <stdint.h>

typedef __attribute__((ext_vector_type(8))) _Float16 f16x8;
typedef __attribute__((ext_vector_type(4))) _Float16 f16x4;
typedef __attribute__((ext_vector_type(4))) float f32x4;

__device__ __forceinline__ void split4(const f32x4 v, f16x4 &h, f16x4 &l) {
    #pragma unroll
    for (int i = 0; i < 4; ++i) {
        float a = v[i];
        _Float16 hh = (_Float16)a;        // v_cvt_f16_f32 (RNE)
        h[i] = hh;
        l[i] = (_Float16)(a - (float)hh); // residual, rel err ~2^-24
    }
}

// ================= pre-split: f32 [rows x 4096] -> f16 hi/lo planes =================
// dst has dstRows (>= srcRows); rows >= srcRows zero-filled. cols fixed = 4096.
__global__ __launch_bounds__(256)
void split_rows(const float* __restrict__ src, _Float16* __restrict__ h,
                _Float16* __restrict__ l, int srcRows, long long total4)
{
    const long long stride = (long long)gridDim.x * blockDim.x;
    for (long long i = (long long)blockIdx.x * blockDim.x + threadIdx.x; i < total4; i += stride) {
        const long long e = i << 2;
        const int row = (int)(e >> 12);      // cols = 4096
        f16x4 hv = {}, lv = {};
        if (row < srcRows) {
            f32x4 v = *(const f32x4*)(src + e);
            split4(v, hv, lv);
        }
        *(f16x4*)(h + e) = hv;
        *(f16x4*)(l + e) = lv;
    }
}

// ================= phased 256-wide split-3 GEMM =================
// C[m][n] = act( sum_k A[m][k]*B[n][k] + bias[n] ), A/B given as f16 hi/lo planes.
// BM = MI*32 (MI=8 -> 256), BN = 256, BK = 32, 8 waves (2M x 4N), dbuf LDS.

#define BARRIER() __builtin_amdgcn_s_barrier()
#define LGKM0() do { asm volatile("s_waitcnt lgkmcnt(0)" ::: "memory"); __builtin_amdgcn_sched_barrier(0); } while (0)
#define VMC0()  do { asm volatile("s_waitcnt vmcnt(0)"  ::: "memory"); __builtin_amdgcn_sched_barrier(0); } while (0)

__device__ __forceinline__ void gload16(const _Float16* g, _Float16* l) {
    __builtin_amdgcn_global_load_lds(
        (const __attribute__((address_space(1))) void*)g,
        (__attribute__((address_space(3))) void*)l, 16, 0, 0);
}

template<int MI, bool SPLITOUT>
__global__ __launch_bounds__(512, 2)
void gemm3_phase(const _Float16* __restrict__ Agh, const _Float16* __restrict__ Agl,
                 const _Float16* __restrict__ Bgh, const _Float16* __restrict__ Bgl,
                 const float* __restrict__ bias,
                 _Float16* __restrict__ Oh, _Float16* __restrict__ Ol,
                 float* __restrict__ Of, int ldo, int Nstore,
                 int K, int nBM)
{
    extern __shared__ _Float16 lds[];
    constexpr int WROWS = MI * 16;           // per-wave rows
    constexpr int BM    = MI * 32;
    constexpr int CHA   = MI * 2;            // 1KB chunks per A plane
    constexpr int PW    = (2*CHA + 32) / 8;  // staging chunks per wave (8 or 6)
    constexpr int ALO   = CHA * 512;         // Al base (halfs)
    constexpr int BHO   = 2 * CHA * 512;     // Bh base
    constexpr int BUFS  = 2*CHA*512 + 16384; // halfs per buffer
    constexpr int S1 = (PW == 8) ? 3 : 2;    // stage-group splits
    constexpr int S2 = (PW == 8) ? 6 : 4;

    const int tid  = threadIdx.x;
    const int lane = tid & 63;
    const int wave = tid >> 6;
    const int wm = wave >> 2;                // 0..1
    const int wn = wave & 3;                 // 0..3
    const int fr = lane & 15;
    const int fg = lane >> 4;

    // XCD-aware block swizzle (gridDim.x % 8 == 0 for both launches)
    const int nwg  = gridDim.x;
    const int cpx  = nwg >> 3;
    const int orig = blockIdx.x;
    const int swzb = (orig & 7) * cpx + (orig >> 3);
    const int bm = swzb % nBM;
    const int bn = swzb / nBM;
    const int m0 = bm * BM;
    const int n0 = bn * 256;

    // ---- staging descriptors: global src pre-XOR-swizzled, LDS dest linear ----
    const _Float16* gptr[8];
    int loff[8];
    #pragma unroll
    for (int i = 0; i < PW; ++i) {
        const int ch = wave * PW + i;
        int p, q;
        if      (ch < CHA)        { p = 0; q = ch; }
        else if (ch < 2*CHA)      { p = 1; q = ch - CHA; }
        else if (ch < 2*CHA + 16) { p = 2; q = ch - 2*CHA; }
        else                      { p = 3; q = ch - 2*CHA - 16; }
        const int row = q*16 + (lane >> 2);
        const int gc  = (lane & 3) ^ ((row >> 1) & 3);
        const _Float16* plane = (p == 0) ? Agh : (p == 1) ? Agl : (p == 2) ? Bgh : Bgl;
        const size_t grow = (size_t)((p < 2) ? m0 : n0) + row;
        gptr[i] = plane + grow * (size_t)K + gc * 8;
        loff[i] = ((p < 2) ? p * ALO : BHO + (p - 2) * 8192) + q * 512;
    }

    // ---- fragment ds_read offsets (swizzled) ----
    const int swz8 = (fg ^ ((fr >> 1) & 3)) * 8;
    int aoff[MI], boff[4];
    #pragma unroll
    for (int mi = 0; mi < MI; ++mi) aoff[mi] = (wm*WROWS + mi*16 + fr)*32 + swz8;
    #pragma unroll
    for (int ni = 0; ni < 4; ++ni)  boff[ni] = BHO + (wn*64 + ni*16 + fr)*32 + swz8;

    f32x4 acc[MI][4] = {};

    // prologue: stage K-tile 0 into buf0
    #pragma unroll
    for (int i = 0; i < PW; ++i) { gload16(gptr[i], &lds[loff[i]]); gptr[i] += 32; }
    VMC0(); BARRIER();

    const int NT = K >> 5;
    int bb = 0;
    for (int t = 0; t < NT; ++t) {
        const int  nb = BUFS - bb;
        const bool st = (t < NT - 1);
        f16x8 ah[MI], al[MI], bhf, blf;

#define PHASE(NI, SBEG, SEND, LAST) do {                                              \
        bhf = *(const f16x8*)&lds[bb + boff[NI]];                                     \
        blf = *(const f16x8*)&lds[bb + 8192 + boff[NI]];                              \
        if (st) {                                                                     \
            _Pragma("unroll")                                                         \
            for (int i = (SBEG); i < (SEND); ++i) {                                   \
                gload16(gptr[i], &lds[nb + loff[i]]); gptr[i] += 32;                  \
            }                                                                         \
        }                                                                             \
        BARRIER(); LGKM0();                                                           \
        __builtin_amdgcn_s_setprio(1);                                                \
        _Pragma("unroll")                                                             \
        for (int mi = 0; mi < MI; ++mi) {                                             \
            acc[mi][NI] = __builtin_amdgcn_mfma_f32_16x16x32_f16(ah[mi], bhf, acc[mi][NI], 0, 0, 0); \
            acc[mi][NI] = __builtin_amdgcn_mfma_f32_16x16x32_f16(ah[mi], blf, acc[mi][NI], 0, 0, 0); \
            acc[mi][NI] = __builtin_amdgcn_mfma_f32_16x16x32_f16(al[mi], bhf, acc[mi][NI], 0, 0, 0); \
        }                                                                             \
        __builtin_amdgcn_s_setprio(0);                                                \
        if (LAST) VMC0();                                                             \
        BARRIER();                                                                    \
    } while (0)

        // P1: A-fragments (all mi, both planes) + B0
        #pragma unroll
        for (int mi = 0; mi < MI; ++mi) {
            ah[mi] = *(const f16x8*)&lds[bb + aoff[mi]];
            al[mi] = *(const f16x8*)&lds[bb + ALO + aoff[mi]];
        }
        PHASE(0, 0, S1, false);
        PHASE(1, S1, S2, false);
        PHASE(2, S2, PW, false);
        PHASE(3, 0, 0, true);
#undef PHASE
        bb = nb;
    }

    // ---- epilogue: bias (+ReLU+split | f32 store) ----
    // D mapping (HW-verified): n = lane&15, m = (lane>>4)*4 + reg
    #pragma unroll
    for (int ni = 0; ni < 4; ++ni) {
        const int n = n0 + wn*64 + ni*16 + fr;
        if (!SPLITOUT && n >= Nstore) continue;
        const float bv = bias[n];
        #pragma unroll
        for (int mi = 0; mi < MI; ++mi) {
            #pragma unroll
            for (int j = 0; j < 4; ++j) {
                const int m = m0 + wm*WROWS + mi*16 + fg*4 + j;
                float v = acc[mi][ni][j] + bv;
                if (SPLITOUT) {
                    v = fmaxf(v, 0.f);
                    const _Float16 hh = (_Float16)v;
                    Oh[(size_t)m * ldo + n] = hh;
                    Ol[(size_t)m * ldo + n] = (_Float16)(v - (float)hh);
                } else {
                    Of[(size_t)m * ldo + n] = v;
                }
            }
        }
    }
}

// ================= fallback path (R2, known-passing) =================
#define TILE_M 128
#define TILE_N 128
#define TILE_K 32
#define LDSK   40

template<bool RELU, bool NGUARD>
__global__ __launch_bounds__(256, 2)
void gemm_split3(const float* __restrict__ A, const float* __restrict__ B,
                 const float* __restrict__ bias, float* __restrict__ C,
                 int K, int ldc, int Nreal)
{
    __shared__ _Float16 Ah[TILE_M][LDSK];
    __shared__ _Float16 Al[TILE_M][LDSK];
    __shared__ _Float16 Bh[TILE_N][LDSK];
    __shared__ _Float16 Bl[TILE_N][LDSK];

    const int tid  = threadIdx.x;
    const int lane = tid & 63;
    const int wave = tid >> 6;
    const int wr   = wave >> 1;
    const int wc   = wave & 1;
    const int m0   = blockIdx.x * TILE_M;
    const int n0   = blockIdx.y * TILE_N;
    const int srow = tid >> 3;
    const int scol = (tid & 7) << 2;
    const int fr = lane & 15;
    const int fg = lane >> 4;

    f32x4 acc[4][4] = {};

    for (int kt = 0; kt < K; kt += TILE_K) {
        __syncthreads();
        #pragma unroll
        for (int p = 0; p < 4; ++p) {
            const int row = srow + p * 32;
            f32x4 v = *(const f32x4*)(A + (size_t)(m0 + row) * K + kt + scol);
            f16x4 hv, lv;
            split4(v, hv, lv);
            *(f16x4*)&Ah[row][scol] = hv;
            *(f16x4*)&Al[row][scol] = lv;
        }
        #pragma unroll
        for (int p = 0; p < 4; ++p) {
            const int row = srow + p * 32;
            f32x4 v = {0.f, 0.f, 0.f, 0.f};
            if (!NGUARD || (n0 + row) < Nreal)
                v = *(const f32x4*)(B + (size_t)(n0 + row) * K + kt + scol);
            f16x4 hv, lv;
            split4(v, hv, lv);
            *(f16x4*)&Bh[row][scol] = hv;
            *(f16x4*)&Bl[row][scol] = lv;
        }
        __syncthreads();

        f16x8 ah[4], al[4];
        #pragma unroll
        for (int mi = 0; mi < 4; ++mi) {
            const int r = wr * 64 + mi * 16 + fr;
            ah[mi] = *(const f16x8*)&Ah[r][fg * 8];
            al[mi] = *(const f16x8*)&Al[r][fg * 8];
        }
        #pragma unroll
        for (int ni = 0; ni < 4; ++ni) {
            const int r = wc * 64 + ni * 16 + fr;
            const f16x8 bh = *(const f16x8*)&Bh[r][fg * 8];
            const f16x8 bl = *(const f16x8*)&Bl[r][fg * 8];
            #pragma unroll
            for (int mi = 0; mi < 4; ++mi) {
                acc[mi][ni] = __builtin_amdgcn_mfma_f32_16x16x32_f16(ah[mi], bh, acc[mi][ni], 0, 0, 0);
                acc[mi][ni] = __builtin_amdgcn_mfma_f32_16x16x32_f16(ah[mi], bl, acc[mi][ni], 0, 0, 0);
                acc[mi][ni] = __builtin_amdgcn_mfma_f32_16x16x32_f16(al[mi], bh, acc[mi][ni], 0, 0, 0);
            }
        }
    }

    #pragma unroll
    for (int ni = 0; ni < 4; ++ni) {
        const int n = n0 + wc * 64 + ni * 16 + fr;
        if (NGUARD && n >= Nreal) continue;
        const float bv = bias[n];
        #pragma unroll
        for (int mi = 0; mi < 4; ++mi) {
            #pragma unroll
            for (int j = 0; j < 4; ++j) {
                const int m = m0 + wr * 64 + mi * 16 + fg * 4 + j;
                float val = acc[mi][ni][j] + bv;
                if (RELU) val = fmaxf(val, 0.f);
                C[(size_t)m * ldc + n] = val;
            }
        }
    }
}

// In-place row softmax: one wave per row (cols <= 1024).
__global__ __launch_bounds__(256)
void softmax_rows(float* __restrict__ out, int rows, int cols)
{
    const int lane = threadIdx.x & 63;
    const int row  = blockIdx.x * 4 + (threadIdx.x >> 6);
    if (row >= rows) return;
    float* p = out + (size_t)row * cols;

    float v[16];
    float mx = -3.4e38f;
    #pragma unroll
    for (int j = 0; j < 16; ++j) {
        const int c = lane + j * 64;
        v[j] = (c < cols) ? p[c] : -3.4e38f;
        mx = fmaxf(mx, v[j]);
    }
    #pragma unroll
    for (int off = 32; off > 0; off >>= 1)
        mx = fmaxf(mx, __shfl_xor(mx, off));

    float s = 0.f;
    #pragma unroll
    for (int j = 0; j < 16; ++j) {
        const int c = lane + j * 64;
        const float e = (c < cols) ? __expf(v[j] - mx) : 0.f;
        v[j] = e;
        s += e;
    }
    #pragma unroll
    for (int off = 32; off > 0; off >>= 1)
        s += __shfl_xor(s, off);

    const float inv = 1.f / s;
    #pragma unroll
    for (int j = 0; j < 16; ++j) {
        const int c = lane + j * 64;
        if (c < cols) p[c] = v[j] * inv;
    }
}

// ================= host =================
extern "C" void kernel_launch(void* const* d_in, const int* in_sizes, int n_in,
                              void* d_out, int out_size, void* d_ws, size_t ws_size,
                              hipStream_t stream)
{
    const float* x  = (const float*)d_in[0];   // [8192, 4096]
    const float* w1 = (const float*)d_in[1];   // [4096, 4096]
    const float* b1 = (const float*)d_in[2];   // [4096]
    const float* w2 = (const float*)d_in[3];   // [1000, 4096]
    const float* b2 = (const float*)d_in[4];   // [1000]
    float* out = (float*)d_out;                // [8192, 1000] fp32

    const size_t SZ_X  = (size_t)8192 * 4096 * 2;   // one f16 plane of x / act
    const size_t SZ_W1 = (size_t)4096 * 4096 * 2;
    const size_t SZ_W2 = (size_t)1024 * 4096 * 2;   // padded to 1024 rows

    size_t off = 0;
    auto take = [&](size_t b) { size_t o = off; off += (b + 255) & ~(size_t)255; return o; };
    const size_t o_xh  = take(SZ_X),  o_xl  = take(SZ_X);
    const size_t o_w1h = take(SZ_W1), o_w1l = take(SZ_W1);
    const size_t o_w2h = take(SZ_W2), o_w2l = take(SZ_W2);
    const size_t o_ah  = take(SZ_X),  o_al  = take(SZ_X);
    const size_t need = off;

    bool attr_ok =
        (hipFuncSetAttribute((const void*)gemm3_phase<8, true>,
                             hipFuncAttributeMaxDynamicSharedMemorySize, 131072) == hipSuccess) &&
        (hipFuncSetAttribute((const void*)gemm3_phase<4, false>,
                             hipFuncAttributeMaxDynamicSharedMemorySize, 131072) == hipSuccess);

    const dim3 blk256(256, 1, 1), blk512(512, 1, 1);

    if (attr_ok && ws_size >= need) {
        char* w = (char*)d_ws;
        _Float16 *xh  = (_Float16*)(w + o_xh),  *xl  = (_Float16*)(w + o_xl);
        _Float16 *w1h = (_Float16*)(w + o_w1h), *w1l = (_Float16*)(w + o_w1l);
        _Float16 *w2h = (_Float16*)(w + o_w2h), *w2l = (_Float16*)(w + o_w2l);
        _Float16 *ath = (_Float16*)(w + o_ah),  *atl = (_Float16*)(w + o_al);

        hipLaunchKernelGGL(split_rows, dim3(2048), blk256, 0, stream, x,  xh,  xl,  8192, (long long)8192 * 1024);
        hipLaunchKernelGGL(split_rows, dim3(2048), blk256, 0, stream, w1, w1h, w1l, 4096, (long long)4096 * 1024);
        hipLaunchKernelGGL(split_rows, dim3(1024), blk256, 0, stream, w2, w2h, w2l, 1000, (long long)1024 * 1024);

        // GEMM1: act(hi/lo) = relu(x @ w1^T + b1)   M=8192 N=4096 K=4096, BM=256
        hipLaunchKernelGGL((gemm3_phase<8, true>), dim3(512), blk512, 131072, stream,
                           xh, xl, w1h, w1l, b1, ath, atl, (float*)nullptr, 4096, 4096, 4096, 32);
        // GEMM2: logits = act @ w2^T + b2           M=8192 N=1024(pad) K=4096, BM=128
        hipLaunchKernelGGL((gemm3_phase<4, false>), dim3(256), blk512, 98304, stream,
                           ath, atl, w2h, w2l, b2, (_Float16*)nullptr, (_Float16*)nullptr,
                           out, 1000, 1000, 4096, 64);
        hipLaunchKernelGGL(softmax_rows, dim3(2048), blk256, 0, stream, out, 8192, 1000);
    } else {
        // fallback: R2 path (act as f32 in ws)
        float* act = (float*)d_ws;
        hipLaunchKernelGGL((gemm_split3<true, false>), dim3(64, 32), blk256, 0, stream,
                           x, w1, b1, act, 4096, 4096, 4096);
        hipLaunchKernelGGL((gemm_split3<false, true>), dim3(64, 8), blk256, 0, stream,
                           act, w2, b2, out, 4096, 1000, 1000);
        hipLaunchKernelGGL(softmax_rows, dim3(2048), blk256, 0, stream, out, 8192, 1000);
    }
}

// Round 4
// 1013.166 us; speedup vs baseline: 1.2612x; 1.0229x over previous
//
#include <hip/hip_runtime.h>
#include <hip/hip_fp16.h>
#include <stdint.h>

typedef __attribute__((ext_vector_type(8))) _Float16 f16x8;
typedef __attribute__((ext_vector_type(4))) _Float16 f16x4;
typedef __attribute__((ext_vector_type(4))) float f32x4;

__device__ __forceinline__ void split4(const f32x4 v, f16x4 &h, f16x4 &l) {
    #pragma unroll
    for (int i = 0; i < 4; ++i) {
        float a = v[i];
        _Float16 hh = (_Float16)a;        // v_cvt_f16_f32 (RNE)
        h[i] = hh;
        l[i] = (_Float16)(a - (float)hh); // residual, rel err ~2^-24
    }
}

// ================= pre-split: f32 [rows x 4096] -> f16 hi/lo planes =================
__global__ __launch_bounds__(256)
void split_rows(const float* __restrict__ src, _Float16* __restrict__ h,
                _Float16* __restrict__ l, int srcRows, long long total4)
{
    const long long stride = (long long)gridDim.x * blockDim.x;
    for (long long i = (long long)blockIdx.x * blockDim.x + threadIdx.x; i < total4; i += stride) {
        const long long e = i << 2;
        const int row = (int)(e >> 12);      // cols = 4096
        f16x4 hv = {}, lv = {};
        if (row < srcRows) {
            f32x4 v = *(const f32x4*)(src + e);
            split4(v, hv, lv);
        }
        *(f16x4*)(h + e) = hv;
        *(f16x4*)(l + e) = lv;
    }
}

// ================= phased 256-wide split-3 GEMM, counted-vmcnt pipeline =================
// C[m][n] = act( sum_k A[m][k]*B[n][k] + bias[n] ), A/B given as f16 hi/lo planes.
// BM = MI*32, BN = 256, BK = 32, 8 waves (2M x 4N), dbuf LDS, 4 phases/K-step.

#define BARRIER() __builtin_amdgcn_s_barrier()
#define LGKM0() do { asm volatile("s_waitcnt lgkmcnt(0)" ::: "memory"); __builtin_amdgcn_sched_barrier(0); } while (0)

template<int N> __device__ __forceinline__ void VMCNT() {
    asm volatile("s_waitcnt vmcnt(%0)" :: "n"(N) : "memory");
    __builtin_amdgcn_sched_barrier(0);
}

__device__ __forceinline__ void gload16(const _Float16* g, _Float16* l) {
    __builtin_amdgcn_global_load_lds(
        (const __attribute__((address_space(1))) void*)g,
        (__attribute__((address_space(3))) void*)l, 16, 0, 0);
}

template<int MI, bool SPLITOUT>
__global__ __launch_bounds__(512, 2)
void gemm3_phase(const _Float16* __restrict__ Agh, const _Float16* __restrict__ Agl,
                 const _Float16* __restrict__ Bgh, const _Float16* __restrict__ Bgl,
                 const float* __restrict__ bias,
                 _Float16* __restrict__ Oh, _Float16* __restrict__ Ol,
                 float* __restrict__ Of, int ldo, int Nstore,
                 int K, int nBM)
{
    extern __shared__ _Float16 lds[];
    constexpr int WROWS = MI * 16;           // per-wave rows
    constexpr int BM    = MI * 32;
    constexpr int CHA   = MI * 2;            // 1KB chunks per A plane
    constexpr int PW    = (2*CHA + 32) / 8;  // staging chunks per wave (8 or 6)
    constexpr int NA    = PW - 4;            // A chunks per wave
    constexpr int ALO   = CHA * 512;         // Al base (halfs)
    constexpr int BHO   = 2 * CHA * 512;     // Bh base
    constexpr int BUFS  = 2*CHA*512 + 16384; // halfs per buffer

    const int tid  = threadIdx.x;
    const int lane = tid & 63;
    const int wave = tid >> 6;
    const int wm = wave >> 2;                // 0..1
    const int wn = wave & 3;                 // 0..3
    const int fr = lane & 15;
    const int fg = lane >> 4;

    // XCD-aware block swizzle (gridDim.x % 8 == 0 for both launches)
    const int nwg  = gridDim.x;
    const int cpx  = nwg >> 3;
    const int orig = blockIdx.x;
    const int swzb = (orig & 7) * cpx + (orig >> 3);
    const int bm = swzb % nBM;
    const int bn = swzb / nBM;
    const int m0 = bm * BM;
    const int n0 = bn * 256;

    // ---- staging descriptors ----
    // chunk order per wave = consumption order: A0..A(NA-1), B0, B1, B2, B3
    //   A chunk i: j = wave*NA + i -> plane j/CHA (Ah/Al), q = j%CHA
    //   B chunk ni: q = ni + (wave&3)*4, plane = Bh (wave<4) / Bl (wave>=4)
    // (phase NI reads B rows r with ((r>>4)&3)==NI, i.e. chunks q&3==NI)
    const _Float16* gptr[8];
    int loff[8];
    #pragma unroll
    for (int i = 0; i < PW; ++i) {
        int p, q;
        if (i < NA) {
            const int j = wave * NA + i;
            p = j / CHA; q = j % CHA;
        } else {
            const int ni = i - NA;
            q = ni + (wave & 3) * 4;
            p = 2 + (wave >> 2);
        }
        const int row = q*16 + (lane >> 2);
        const int gc  = (lane & 3) ^ ((row >> 1) & 3);
        const _Float16* plane = (p == 0) ? Agh : (p == 1) ? Agl : (p == 2) ? Bgh : Bgl;
        const size_t grow = (size_t)((p < 2) ? m0 : n0) + row;
        gptr[i] = plane + grow * (size_t)K + gc * 8;
        loff[i] = ((p < 2) ? p * ALO : BHO + (p - 2) * 8192) + q * 512;
    }

    // ---- fragment ds_read offsets (swizzled) ----
    const int swz8 = (fg ^ ((fr >> 1) & 3)) * 8;
    int aoff[MI], boff[4];
    #pragma unroll
    for (int mi = 0; mi < MI; ++mi) aoff[mi] = (wm*WROWS + mi*16 + fr)*32 + swz8;
    #pragma unroll
    for (int ni = 0; ni < 4; ++ni)  boff[ni] = BHO + (wn*64 + ni*16 + fr)*32 + swz8;

    f32x4 acc[MI][4] = {};

    // prologue: stage K-tile 0 into buf0; wait only for A+B0 (leave B1..B3 in flight)
    #pragma unroll
    for (int i = 0; i < PW; ++i) { gload16(gptr[i], &lds[loff[i]]); gptr[i] += 32; }
    VMCNT<3>(); BARRIER();

    const int NT = K >> 5;
    int bb = 0;

#define PH(NI, IB, IE, WAIT) do {                                                     \
        bhf = *(const f16x8*)&lds[bb + boff[NI]];                                     \
        blf = *(const f16x8*)&lds[bb + 8192 + boff[NI]];                              \
        _Pragma("unroll")                                                             \
        for (int i = (IB); i < (IE); ++i) {                                           \
            gload16(gptr[i], &lds[nb + loff[i]]); gptr[i] += 32;                      \
        }                                                                             \
        BARRIER(); LGKM0();                                                           \
        __builtin_amdgcn_s_setprio(1);                                                \
        _Pragma("unroll")                                                             \
        for (int mi = 0; mi < MI; ++mi) {                                             \
            acc[mi][NI] = __builtin_amdgcn_mfma_f32_16x16x32_f16(ah[mi], bhf, acc[mi][NI], 0, 0, 0); \
            acc[mi][NI] = __builtin_amdgcn_mfma_f32_16x16x32_f16(ah[mi], blf, acc[mi][NI], 0, 0, 0); \
            acc[mi][NI] = __builtin_amdgcn_mfma_f32_16x16x32_f16(al[mi], bhf, acc[mi][NI], 0, 0, 0); \
        }                                                                             \
        __builtin_amdgcn_s_setprio(0);                                                \
        WAIT;                                                                         \
        BARRIER();                                                                    \
    } while (0)

    for (int t = 0; t < NT - 1; ++t) {
        const int nb = BUFS - bb;
        f16x8 ah[MI], al[MI], bhf, blf;
        #pragma unroll
        for (int mi = 0; mi < MI; ++mi) {
            ah[mi] = *(const f16x8*)&lds[bb + aoff[mi]];
            al[mi] = *(const f16x8*)&lds[bb + ALO + aoff[mi]];
        }
        // counted waits: never drain to 0 in the main loop (T4)
        PH(0, 0,    NA,   VMCNT<PW-2>());   // issue A(nxt);  need B1(cur)
        PH(1, NA,   NA+2, VMCNT<PW-1>());   // issue B0,B1;   need B2(cur)
        PH(2, NA+2, PW,   VMCNT<PW>());     // issue B2,B3;   need B3(cur)
        PH(3, 0,    0,    VMCNT<3>());      //                need A+B0(nxt)
        bb = nb;
    }
    {   // peeled last tile: no staging, drain progressively
        const int nb = BUFS - bb;
        f16x8 ah[MI], al[MI], bhf, blf;
        #pragma unroll
        for (int mi = 0; mi < MI; ++mi) {
            ah[mi] = *(const f16x8*)&lds[bb + aoff[mi]];
            al[mi] = *(const f16x8*)&lds[bb + ALO + aoff[mi]];
        }
        PH(0, 0, 0, VMCNT<2>());
        PH(1, 0, 0, VMCNT<1>());
        PH(2, 0, 0, VMCNT<0>());
        PH(3, 0, 0, );
        (void)nb;
    }
#undef PH

    // ---- epilogue: bias (+ReLU+split | f32 store) ----
    // D mapping (HW-verified): n = lane&15, m = (lane>>4)*4 + reg
    #pragma unroll
    for (int ni = 0; ni < 4; ++ni) {
        const int n = n0 + wn*64 + ni*16 + fr;
        if (!SPLITOUT && n >= Nstore) continue;
        const float bv = bias[n];
        #pragma unroll
        for (int mi = 0; mi < MI; ++mi) {
            #pragma unroll
            for (int j = 0; j < 4; ++j) {
                const int m = m0 + wm*WROWS + mi*16 + fg*4 + j;
                float v = acc[mi][ni][j] + bv;
                if (SPLITOUT) {
                    v = fmaxf(v, 0.f);
                    const _Float16 hh = (_Float16)v;
                    Oh[(size_t)m * ldo + n] = hh;
                    Ol[(size_t)m * ldo + n] = (_Float16)(v - (float)hh);
                } else {
                    Of[(size_t)m * ldo + n] = v;
                }
            }
        }
    }
}

// ================= fallback path (R2, known-passing) =================
#define TILE_M 128
#define TILE_N 128
#define TILE_K 32
#define LDSK   40

template<bool RELU, bool NGUARD>
__global__ __launch_bounds__(256, 2)
void gemm_split3(const float* __restrict__ A, const float* __restrict__ B,
                 const float* __restrict__ bias, float* __restrict__ C,
                 int K, int ldc, int Nreal)
{
    __shared__ _Float16 Ah[TILE_M][LDSK];
    __shared__ _Float16 Al[TILE_M][LDSK];
    __shared__ _Float16 Bh[TILE_N][LDSK];
    __shared__ _Float16 Bl[TILE_N][LDSK];

    const int tid  = threadIdx.x;
    const int lane = tid & 63;
    const int wave = tid >> 6;
    const int wr   = wave >> 1;
    const int wc   = wave & 1;
    const int m0   = blockIdx.x * TILE_M;
    const int n0   = blockIdx.y * TILE_N;
    const int srow = tid >> 3;
    const int scol = (tid & 7) << 2;
    const int fr = lane & 15;
    const int fg = lane >> 4;

    f32x4 acc[4][4] = {};

    for (int kt = 0; kt < K; kt += TILE_K) {
        __syncthreads();
        #pragma unroll
        for (int p = 0; p < 4; ++p) {
            const int row = srow + p * 32;
            f32x4 v = *(const f32x4*)(A + (size_t)(m0 + row) * K + kt + scol);
            f16x4 hv, lv;
            split4(v, hv, lv);
            *(f16x4*)&Ah[row][scol] = hv;
            *(f16x4*)&Al[row][scol] = lv;
        }
        #pragma unroll
        for (int p = 0; p < 4; ++p) {
            const int row = srow + p * 32;
            f32x4 v = {0.f, 0.f, 0.f, 0.f};
            if (!NGUARD || (n0 + row) < Nreal)
                v = *(const f32x4*)(B + (size_t)(n0 + row) * K + kt + scol);
            f16x4 hv, lv;
            split4(v, hv, lv);
            *(f16x4*)&Bh[row][scol] = hv;
            *(f16x4*)&Bl[row][scol] = lv;
        }
        __syncthreads();

        f16x8 ah[4], al[4];
        #pragma unroll
        for (int mi = 0; mi < 4; ++mi) {
            const int r = wr * 64 + mi * 16 + fr;
            ah[mi] = *(const f16x8*)&Ah[r][fg * 8];
            al[mi] = *(const f16x8*)&Al[r][fg * 8];
        }
        #pragma unroll
        for (int ni = 0; ni < 4; ++ni) {
            const int r = wc * 64 + ni * 16 + fr;
            const f16x8 bh = *(const f16x8*)&Bh[r][fg * 8];
            const f16x8 bl = *(const f16x8*)&Bl[r][fg * 8];
            #pragma unroll
            for (int mi = 0; mi < 4; ++mi) {
                acc[mi][ni] = __builtin_amdgcn_mfma_f32_16x16x32_f16(ah[mi], bh, acc[mi][ni], 0, 0, 0);
                acc[mi][ni] = __builtin_amdgcn_mfma_f32_16x16x32_f16(ah[mi], bl, acc[mi][ni], 0, 0, 0);
                acc[mi][ni] = __builtin_amdgcn_mfma_f32_16x16x32_f16(al[mi], bh, acc[mi][ni], 0, 0, 0);
            }
        }
    }

    #pragma unroll
    for (int ni = 0; ni < 4; ++ni) {
        const int n = n0 + wc * 64 + ni * 16 + fr;
        if (NGUARD && n >= Nreal) continue;
        const float bv = bias[n];
        #pragma unroll
        for (int mi = 0; mi < 4; ++mi) {
            #pragma unroll
            for (int j = 0; j < 4; ++j) {
                const int m = m0 + wr * 64 + mi * 16 + fg * 4 + j;
                float val = acc[mi][ni][j] + bv;
                if (RELU) val = fmaxf(val, 0.f);
                C[(size_t)m * ldc + n] = val;
            }
        }
    }
}

// In-place row softmax: one wave per row (cols <= 1024).
__global__ __launch_bounds__(256)
void softmax_rows(float* __restrict__ out, int rows, int cols)
{
    const int lane = threadIdx.x & 63;
    const int row  = blockIdx.x * 4 + (threadIdx.x >> 6);
    if (row >= rows) return;
    float* p = out + (size_t)row * cols;

    float v[16];
    float mx = -3.4e38f;
    #pragma unroll
    for (int j = 0; j < 16; ++j) {
        const int c = lane + j * 64;
        v[j] = (c < cols) ? p[c] : -3.4e38f;
        mx = fmaxf(mx, v[j]);
    }
    #pragma unroll
    for (int off = 32; off > 0; off >>= 1)
        mx = fmaxf(mx, __shfl_xor(mx, off));

    float s = 0.f;
    #pragma unroll
    for (int j = 0; j < 16; ++j) {
        const int c = lane + j * 64;
        const float e = (c < cols) ? __expf(v[j] - mx) : 0.f;
        v[j] = e;
        s += e;
    }
    #pragma unroll
    for (int off = 32; off > 0; off >>= 1)
        s += __shfl_xor(s, off);

    const float inv = 1.f / s;
    #pragma unroll
    for (int j = 0; j < 16; ++j) {
        const int c = lane + j * 64;
        if (c < cols) p[c] = v[j] * inv;
    }
}

// ================= host =================
extern "C" void kernel_launch(void* const* d_in, const int* in_sizes, int n_in,
                              void* d_out, int out_size, void* d_ws, size_t ws_size,
                              hipStream_t stream)
{
    const float* x  = (const float*)d_in[0];   // [8192, 4096]
    const float* w1 = (const float*)d_in[1];   // [4096, 4096]
    const float* b1 = (const float*)d_in[2];   // [4096]
    const float* w2 = (const float*)d_in[3];   // [1000, 4096]
    const float* b2 = (const float*)d_in[4];   // [1000]
    float* out = (float*)d_out;                // [8192, 1000] fp32

    const size_t SZ_X  = (size_t)8192 * 4096 * 2;   // one f16 plane of x / act
    const size_t SZ_W1 = (size_t)4096 * 4096 * 2;
    const size_t SZ_W2 = (size_t)1024 * 4096 * 2;   // padded to 1024 rows

    size_t off = 0;
    auto take = [&](size_t b) { size_t o = off; off += (b + 255) & ~(size_t)255; return o; };
    const size_t o_xh  = take(SZ_X),  o_xl  = take(SZ_X);
    const size_t o_w1h = take(SZ_W1), o_w1l = take(SZ_W1);
    const size_t o_w2h = take(SZ_W2), o_w2l = take(SZ_W2);
    const size_t o_ah  = take(SZ_X),  o_al  = take(SZ_X);
    const size_t need = off;

    bool attr_ok =
        (hipFuncSetAttribute((const void*)gemm3_phase<8, true>,
                             hipFuncAttributeMaxDynamicSharedMemorySize, 131072) == hipSuccess) &&
        (hipFuncSetAttribute((const void*)gemm3_phase<4, false>,
                             hipFuncAttributeMaxDynamicSharedMemorySize, 131072) == hipSuccess);

    const dim3 blk256(256, 1, 1), blk512(512, 1, 1);

    if (attr_ok && ws_size >= need) {
        char* w = (char*)d_ws;
        _Float16 *xh  = (_Float16*)(w + o_xh),  *xl  = (_Float16*)(w + o_xl);
        _Float16 *w1h = (_Float16*)(w + o_w1h), *w1l = (_Float16*)(w + o_w1l);
        _Float16 *w2h = (_Float16*)(w + o_w2h), *w2l = (_Float16*)(w + o_w2l);
        _Float16 *ath = (_Float16*)(w + o_ah),  *atl = (_Float16*)(w + o_al);

        hipLaunchKernelGGL(split_rows, dim3(2048), blk256, 0, stream, x,  xh,  xl,  8192, (long long)8192 * 1024);
        hipLaunchKernelGGL(split_rows, dim3(2048), blk256, 0, stream, w1, w1h, w1l, 4096, (long long)4096 * 1024);
        hipLaunchKernelGGL(split_rows, dim3(1024), blk256, 0, stream, w2, w2h, w2l, 1000, (long long)1024 * 1024);

        // GEMM1: act(hi/lo) = relu(x @ w1^T + b1)   M=8192 N=4096 K=4096, BM=256
        hipLaunchKernelGGL((gemm3_phase<8, true>), dim3(512), blk512, 131072, stream,
                           xh, xl, w1h, w1l, b1, ath, atl, (float*)nullptr, 4096, 4096, 4096, 32);
        // GEMM2: logits = act @ w2^T + b2           M=8192 N=1024(pad) K=4096, BM=128
        hipLaunchKernelGGL((gemm3_phase<4, false>), dim3(256), blk512, 98304, stream,
                           ath, atl, w2h, w2l, b2, (_Float16*)nullptr, (_Float16*)nullptr,
                           out, 1000, 1000, 4096, 64);
        hipLaunchKernelGGL(softmax_rows, dim3(2048), blk256, 0, stream, out, 8192, 1000);
    } else {
        // fallback: R2 path (act as f32 in ws)
        float* act = (float*)d_ws;
        hipLaunchKernelGGL((gemm_split3<true, false>), dim3(64, 32), blk256, 0, stream,
                           x, w1, b1, act, 4096, 4096, 4096);
        hipLaunchKernelGGL((gemm_split3<false, true>), dim3(64, 8), blk256, 0, stream,
                           act, w2, b2, out, 4096, 1000, 1000);
        hipLaunchKernelGGL(softmax_rows, dim3(2048), blk256, 0, stream, out, 8192, 1000);
    }
}

// Round 5
// 969.818 us; speedup vs baseline: 1.3176x; 1.0447x over previous
//
#include <hip/hip_runtime.h>
#include <hip/hip_fp16.h>
#include <stdint.h>

typedef __attribute__((ext_vector_type(8))) _Float16 f16x8;
typedef __attribute__((ext_vector_type(4))) _Float16 f16x4;
typedef __attribute__((ext_vector_type(4))) float f32x4;

__device__ __forceinline__ void split4(const f32x4 v, f16x4 &h, f16x4 &l) {
    #pragma unroll
    for (int i = 0; i < 4; ++i) {
        float a = v[i];
        _Float16 hh = (_Float16)a;        // v_cvt_f16_f32 (RNE)
        h[i] = hh;
        l[i] = (_Float16)(a - (float)hh); // residual, rel err ~2^-24
    }
}

// ================= pre-split: f32 [rows x 4096] -> f16 hi/lo planes =================
__global__ __launch_bounds__(256)
void split_rows(const float* __restrict__ src, _Float16* __restrict__ h,
                _Float16* __restrict__ l, int srcRows, long long total4)
{
    const long long stride = (long long)gridDim.x * blockDim.x;
    for (long long i = (long long)blockIdx.x * blockDim.x + threadIdx.x; i < total4; i += stride) {
        const long long e = i << 2;
        const int row = (int)(e >> 12);      // cols = 4096
        f16x4 hv = {}, lv = {};
        if (row < srcRows) {
            f32x4 v = *(const f32x4*)(src + e);
            split4(v, hv, lv);
        }
        *(f16x4*)(h + e) = hv;
        *(f16x4*)(l + e) = lv;
    }
}

// ================= split-3 GEMM, 2-sync-per-K-step counted-vmcnt pipeline =================
// C[m][n] = act( sum_k A[m][k]*B[n][k] + bias[n] ), A/B as f16 hi/lo planes.
// BM = MI*32, BN = 256, BK = 32, 8 waves (2M x 4N), dbuf LDS.
// Sync invariant: every barrier is preceded by each wave's vmcnt covering its own
// staged chunks for the region consumed after that barrier. Waits never 0 mid-loop.

#define BARRIER() __builtin_amdgcn_s_barrier()
#define SB0()     __builtin_amdgcn_sched_barrier(0)
#define MFMA16    __builtin_amdgcn_mfma_f32_16x16x32_f16

template<int N> __device__ __forceinline__ void VMCNT() {
    asm volatile("s_waitcnt vmcnt(%0)" :: "n"(N) : "memory");
    __builtin_amdgcn_sched_barrier(0);
}

__device__ __forceinline__ void gload16(const _Float16* g, _Float16* l) {
    __builtin_amdgcn_global_load_lds(
        (const __attribute__((address_space(1))) void*)g,
        (__attribute__((address_space(3))) void*)l, 16, 0, 0);
}

template<int MI, bool SPLITOUT, bool CHUNKSWZ>
__global__ __launch_bounds__(512, 2)
void gemm3_v5(const _Float16* __restrict__ Agh, const _Float16* __restrict__ Agl,
              const _Float16* __restrict__ Bgh, const _Float16* __restrict__ Bgl,
              const float* __restrict__ bias,
              _Float16* __restrict__ Oh, _Float16* __restrict__ Ol,
              float* __restrict__ Of, int ldo, int Nstore,
              int K, int nBM)
{
    extern __shared__ _Float16 lds[];
    constexpr int WROWS = MI * 16;
    constexpr int BM    = MI * 32;
    constexpr int CHA   = MI * 2;            // 1KB chunks per A plane
    constexpr int PW    = (2*CHA + 32) / 8;  // chunks per wave (8 or 6)
    constexpr int NA    = PW - 4;            // A chunks per wave
    constexpr int ALO   = CHA * 512;
    constexpr int BHO   = 2 * CHA * 512;
    constexpr int BUFS  = 2*CHA*512 + 16384;

    const int tid  = threadIdx.x;
    const int lane = tid & 63;
    const int wave = tid >> 6;
    const int wm = wave >> 2;
    const int wn = wave & 3;
    const int fr = lane & 15;
    const int fg = lane >> 4;

    // ---- block swizzle ----
    int bm, bn;
    const int orig = blockIdx.x;
    if (CHUNKSWZ) {
        // GEMM1: 512 blocks = 32bm x 16bn. XCD k (= orig&7) owns bm in [4k,4k+4),
        // bn sweeping: concurrent 32 blocks/XCD = 4 A-tiles x 8 B-tiles (L2-resident).
        bm = ((orig & 7) << 2) | ((orig >> 3) & 3);
        bn = orig >> 5;
    } else {
        const int cpx  = gridDim.x >> 3;
        const int swzb = (orig & 7) * cpx + (orig >> 3);
        bm = swzb % nBM;
        bn = swzb / nBM;
    }
    const int m0 = bm * BM;
    const int n0 = bn * 256;

    // ---- staging descriptors (issue order == consumption order) ----
    // per wave: A-chunks i<NA (j = wave*NA+i -> plane j/CHA, q=j%CHA),
    //           B-chunks ni (q = (wave&3)*4+ni, plane Bh if wave<4 else Bl).
    const _Float16* gptr[8];
    int loff[8];
    #pragma unroll
    for (int i = 0; i < PW; ++i) {
        int p, q;
        if (i < NA) {
            const int j = wave * NA + i;
            p = j / CHA; q = j % CHA;
        } else {
            const int ni = i - NA;
            q = ni + (wave & 3) * 4;
            p = 2 + (wave >> 2);
        }
        const int row = q*16 + (lane >> 2);
        const int gc  = (lane & 3) ^ ((row >> 1) & 3);
        const _Float16* plane = (p == 0) ? Agh : (p == 1) ? Agl : (p == 2) ? Bgh : Bgl;
        const size_t grow = (size_t)((p < 2) ? m0 : n0) + row;
        gptr[i] = plane + grow * (size_t)K + gc * 8;
        loff[i] = ((p < 2) ? p * ALO : BHO + (p - 2) * 8192) + q * 512;
    }

    // ---- fragment ds_read offsets (swizzled, matches staging XOR) ----
    const int swz8 = (fg ^ ((fr >> 1) & 3)) * 8;
    int aoff[MI], boff[4];
    #pragma unroll
    for (int mi = 0; mi < MI; ++mi) aoff[mi] = (wm*WROWS + mi*16 + fr)*32 + swz8;
    #pragma unroll
    for (int ni = 0; ni < 4; ++ni)  boff[ni] = BHO + (wn*64 + ni*16 + fr)*32 + swz8;

    f32x4 acc[MI][4] = {};

    // prologue: stage tile 0; wait through B1 (leave B2,B3 in flight)
    #pragma unroll
    for (int i = 0; i < PW; ++i) { gload16(gptr[i], &lds[loff[i]]); gptr[i] += 32; }
    VMCNT<2>(); BARRIER(); SB0();

// one half-step: B pair (NIa,NIb) frags + A JIT per mi; optional staging issue.
// No manual lgkm drains -- compiler inserts partial lgkmcnt between ds_read & MFMA.
#define DO_HALF(NIa, NIb, IB, IE, STG)                                        \
    do {                                                                      \
        const f16x8 bha = *(const f16x8*)&lds[bb + boff[NIa]];                \
        const f16x8 bla = *(const f16x8*)&lds[bb + 8192 + boff[NIa]];         \
        const f16x8 bhb = *(const f16x8*)&lds[bb + boff[NIb]];                \
        const f16x8 blb = *(const f16x8*)&lds[bb + 8192 + boff[NIb]];         \
        if (STG) {                                                            \
            _Pragma("unroll")                                                 \
            for (int i = (IB); i < (IE); ++i) {                               \
                gload16(gptr[i], &lds[nb + loff[i]]); gptr[i] += 32;          \
            }                                                                 \
        }                                                                     \
        SB0();                                                                \
        __builtin_amdgcn_s_setprio(1);                                        \
        _Pragma("unroll")                                                     \
        for (int mi = 0; mi < MI; ++mi) {                                     \
            const f16x8 ah = *(const f16x8*)&lds[bb + aoff[mi]];              \
            const f16x8 al = *(const f16x8*)&lds[bb + ALO + aoff[mi]];        \
            acc[mi][NIa] = MFMA16(ah, bha, acc[mi][NIa], 0, 0, 0);            \
            acc[mi][NIa] = MFMA16(ah, bla, acc[mi][NIa], 0, 0, 0);            \
            acc[mi][NIa] = MFMA16(al, bha, acc[mi][NIa], 0, 0, 0);            \
            acc[mi][NIb] = MFMA16(ah, bhb, acc[mi][NIb], 0, 0, 0);            \
            acc[mi][NIb] = MFMA16(ah, blb, acc[mi][NIb], 0, 0, 0);            \
            acc[mi][NIb] = MFMA16(al, bhb, acc[mi][NIb], 0, 0, 0);            \
        }                                                                     \
        __builtin_amdgcn_s_setprio(0);                                        \
    } while (0)

    const int NT = K >> 5;
    int bb = 0;
    for (int t = 0; t < NT - 1; ++t) {
        const int nb = BUFS - bb;
        // half 1: consume A + B0,B1(cur); issue A(nxt) + B0,B1(nxt)
        DO_HALF(0, 1, 0, NA + 2, true);
        VMCNT<NA + 2>(); BARRIER(); SB0();   // B2,B3(cur) arrived
        // half 2: consume B2,B3(cur); issue B2,B3(nxt)
        DO_HALF(2, 3, NA + 2, PW, true);
        VMCNT<2>(); BARRIER(); SB0();        // A,B0,B1(nxt) arrived
        bb = nb;
    }
    {   // peeled last step: no staging
        const int nb = 0; (void)nb;
        DO_HALF(0, 1, 0, 0, false);
        VMCNT<0>(); BARRIER(); SB0();        // drain B2,B3(last)
        DO_HALF(2, 3, 0, 0, false);
    }
#undef DO_HALF

    // ---- epilogue: bias (+ReLU+split | f32 store) ----
    // D mapping (HW-verified): n = lane&15, m = (lane>>4)*4 + reg
    #pragma unroll
    for (int ni = 0; ni < 4; ++ni) {
        const int n = n0 + wn*64 + ni*16 + fr;
        if (!SPLITOUT && n >= Nstore) continue;
        const float bv = bias[n];
        #pragma unroll
        for (int mi = 0; mi < MI; ++mi) {
            #pragma unroll
            for (int j = 0; j < 4; ++j) {
                const int m = m0 + wm*WROWS + mi*16 + fg*4 + j;
                float v = acc[mi][ni][j] + bv;
                if (SPLITOUT) {
                    v = fmaxf(v, 0.f);
                    const _Float16 hh = (_Float16)v;
                    Oh[(size_t)m * ldo + n] = hh;
                    Ol[(size_t)m * ldo + n] = (_Float16)(v - (float)hh);
                } else {
                    Of[(size_t)m * ldo + n] = v;
                }
            }
        }
    }
}

// ================= fallback path (R2, known-passing) =================
#define TILE_M 128
#define TILE_N 128
#define TILE_K 32
#define LDSK   40

template<bool RELU, bool NGUARD>
__global__ __launch_bounds__(256, 2)
void gemm_split3(const float* __restrict__ A, const float* __restrict__ B,
                 const float* __restrict__ bias, float* __restrict__ C,
                 int K, int ldc, int Nreal)
{
    __shared__ _Float16 Ah[TILE_M][LDSK];
    __shared__ _Float16 Al[TILE_M][LDSK];
    __shared__ _Float16 Bh[TILE_N][LDSK];
    __shared__ _Float16 Bl[TILE_N][LDSK];

    const int tid  = threadIdx.x;
    const int lane = tid & 63;
    const int wave = tid >> 6;
    const int wr   = wave >> 1;
    const int wc   = wave & 1;
    const int m0   = blockIdx.x * TILE_M;
    const int n0   = blockIdx.y * TILE_N;
    const int srow = tid >> 3;
    const int scol = (tid & 7) << 2;
    const int fr = lane & 15;
    const int fg = lane >> 4;

    f32x4 acc[4][4] = {};

    for (int kt = 0; kt < K; kt += TILE_K) {
        __syncthreads();
        #pragma unroll
        for (int p = 0; p < 4; ++p) {
            const int row = srow + p * 32;
            f32x4 v = *(const f32x4*)(A + (size_t)(m0 + row) * K + kt + scol);
            f16x4 hv, lv;
            split4(v, hv, lv);
            *(f16x4*)&Ah[row][scol] = hv;
            *(f16x4*)&Al[row][scol] = lv;
        }
        #pragma unroll
        for (int p = 0; p < 4; ++p) {
            const int row = srow + p * 32;
            f32x4 v = {0.f, 0.f, 0.f, 0.f};
            if (!NGUARD || (n0 + row) < Nreal)
                v = *(const f32x4*)(B + (size_t)(n0 + row) * K + kt + scol);
            f16x4 hv, lv;
            split4(v, hv, lv);
            *(f16x4*)&Bh[row][scol] = hv;
            *(f16x4*)&Bl[row][scol] = lv;
        }
        __syncthreads();

        f16x8 ah[4], al[4];
        #pragma unroll
        for (int mi = 0; mi < 4; ++mi) {
            const int r = wr * 64 + mi * 16 + fr;
            ah[mi] = *(const f16x8*)&Ah[r][fg * 8];
            al[mi] = *(const f16x8*)&Al[r][fg * 8];
        }
        #pragma unroll
        for (int ni = 0; ni < 4; ++ni) {
            const int r = wc * 64 + ni * 16 + fr;
            const f16x8 bh = *(const f16x8*)&Bh[r][fg * 8];
            const f16x8 bl = *(const f16x8*)&Bl[r][fg * 8];
            #pragma unroll
            for (int mi = 0; mi < 4; ++mi) {
                acc[mi][ni] = __builtin_amdgcn_mfma_f32_16x16x32_f16(ah[mi], bh, acc[mi][ni], 0, 0, 0);
                acc[mi][ni] = __builtin_amdgcn_mfma_f32_16x16x32_f16(ah[mi], bl, acc[mi][ni], 0, 0, 0);
                acc[mi][ni] = __builtin_amdgcn_mfma_f32_16x16x32_f16(al[mi], bh, acc[mi][ni], 0, 0, 0);
            }
        }
    }

    #pragma unroll
    for (int ni = 0; ni < 4; ++ni) {
        const int n = n0 + wc * 64 + ni * 16 + fr;
        if (NGUARD && n >= Nreal) continue;
        const float bv = bias[n];
        #pragma unroll
        for (int mi = 0; mi < 4; ++mi) {
            #pragma unroll
            for (int j = 0; j < 4; ++j) {
                const int m = m0 + wr * 64 + mi * 16 + fg * 4 + j;
                float val = acc[mi][ni][j] + bv;
                if (RELU) val = fmaxf(val, 0.f);
                C[(size_t)m * ldc + n] = val;
            }
        }
    }
}

// In-place row softmax: one wave per row (cols <= 1024).
__global__ __launch_bounds__(256)
void softmax_rows(float* __restrict__ out, int rows, int cols)
{
    const int lane = threadIdx.x & 63;
    const int row  = blockIdx.x * 4 + (threadIdx.x >> 6);
    if (row >= rows) return;
    float* p = out + (size_t)row * cols;

    float v[16];
    float mx = -3.4e38f;
    #pragma unroll
    for (int j = 0; j < 16; ++j) {
        const int c = lane + j * 64;
        v[j] = (c < cols) ? p[c] : -3.4e38f;
        mx = fmaxf(mx, v[j]);
    }
    #pragma unroll
    for (int off = 32; off > 0; off >>= 1)
        mx = fmaxf(mx, __shfl_xor(mx, off));

    float s = 0.f;
    #pragma unroll
    for (int j = 0; j < 16; ++j) {
        const int c = lane + j * 64;
        const float e = (c < cols) ? __expf(v[j] - mx) : 0.f;
        v[j] = e;
        s += e;
    }
    #pragma unroll
    for (int off = 32; off > 0; off >>= 1)
        s += __shfl_xor(s, off);

    const float inv = 1.f / s;
    #pragma unroll
    for (int j = 0; j < 16; ++j) {
        const int c = lane + j * 64;
        if (c < cols) p[c] = v[j] * inv;
    }
}

// ================= host =================
extern "C" void kernel_launch(void* const* d_in, const int* in_sizes, int n_in,
                              void* d_out, int out_size, void* d_ws, size_t ws_size,
                              hipStream_t stream)
{
    const float* x  = (const float*)d_in[0];   // [8192, 4096]
    const float* w1 = (const float*)d_in[1];   // [4096, 4096]
    const float* b1 = (const float*)d_in[2];   // [4096]
    const float* w2 = (const float*)d_in[3];   // [1000, 4096]
    const float* b2 = (const float*)d_in[4];   // [1000]
    float* out = (float*)d_out;                // [8192, 1000] fp32

    const size_t SZ_X  = (size_t)8192 * 4096 * 2;
    const size_t SZ_W1 = (size_t)4096 * 4096 * 2;
    const size_t SZ_W2 = (size_t)1024 * 4096 * 2;

    size_t off = 0;
    auto take = [&](size_t b) { size_t o = off; off += (b + 255) & ~(size_t)255; return o; };
    const size_t o_xh  = take(SZ_X),  o_xl  = take(SZ_X);
    const size_t o_w1h = take(SZ_W1), o_w1l = take(SZ_W1);
    const size_t o_w2h = take(SZ_W2), o_w2l = take(SZ_W2);
    const size_t o_ah  = take(SZ_X),  o_al  = take(SZ_X);
    const size_t need = off;

    bool attr_ok =
        (hipFuncSetAttribute((const void*)gemm3_v5<8, true, true>,
                             hipFuncAttributeMaxDynamicSharedMemorySize, 131072) == hipSuccess) &&
        (hipFuncSetAttribute((const void*)gemm3_v5<4, false, false>,
                             hipFuncAttributeMaxDynamicSharedMemorySize, 131072) == hipSuccess);

    const dim3 blk256(256, 1, 1), blk512(512, 1, 1);

    if (attr_ok && ws_size >= need) {
        char* w = (char*)d_ws;
        _Float16 *xh  = (_Float16*)(w + o_xh),  *xl  = (_Float16*)(w + o_xl);
        _Float16 *w1h = (_Float16*)(w + o_w1h), *w1l = (_Float16*)(w + o_w1l);
        _Float16 *w2h = (_Float16*)(w + o_w2h), *w2l = (_Float16*)(w + o_w2l);
        _Float16 *ath = (_Float16*)(w + o_ah),  *atl = (_Float16*)(w + o_al);

        hipLaunchKernelGGL(split_rows, dim3(2048), blk256, 0, stream, x,  xh,  xl,  8192, (long long)8192 * 1024);
        hipLaunchKernelGGL(split_rows, dim3(2048), blk256, 0, stream, w1, w1h, w1l, 4096, (long long)4096 * 1024);
        hipLaunchKernelGGL(split_rows, dim3(1024), blk256, 0, stream, w2, w2h, w2l, 1000, (long long)1024 * 1024);

        // GEMM1: act(hi/lo) = relu(x @ w1^T + b1)   M=8192 N=4096 K=4096, BM=256, chunked swizzle
        hipLaunchKernelGGL((gemm3_v5<8, true, true>), dim3(512), blk512, 131072, stream,
                           xh, xl, w1h, w1l, b1, ath, atl, (float*)nullptr, 4096, 4096, 4096, 32);
        // GEMM2: logits = act @ w2^T + b2           M=8192 N=1024(pad) K=4096, BM=128
        hipLaunchKernelGGL((gemm3_v5<4, false, false>), dim3(256), blk512, 98304, stream,
                           ath, atl, w2h, w2l, b2, (_Float16*)nullptr, (_Float16*)nullptr,
                           out, 1000, 1000, 4096, 64);
        hipLaunchKernelGGL(softmax_rows, dim3(2048), blk256, 0, stream, out, 8192, 1000);
    } else {
        float* act = (float*)d_ws;
        hipLaunchKernelGGL((gemm_split3<true, false>), dim3(64, 32), blk256, 0, stream,
                           x, w1, b1, act, 4096, 4096, 4096);
        hipLaunchKernelGGL((gemm_split3<false, true>), dim3(64, 8), blk256, 0, stream,
                           act, w2, b2, out, 4096, 1000, 1000);
        hipLaunchKernelGGL(softmax_rows, dim3(2048), blk256, 0, stream, out, 8192, 1000);
    }
}